// Round 12
// baseline (446.218 us; speedup 1.0000x reference)
//
#include <hip/hip_runtime.h>
#include <hip/hip_bf16.h>
#include <math.h>

#define HF 128          // hidden / input feature dim
#define GCOUNT 64       // graphs in batch
#define OUTF 64         // final output features
#define NEG 0.2f        // leaky relu slope
#define CH 2048         // edges per partition block
#define BCAP 8192       // per-bucket edge capacity (expected ~4340, +50 sigma)

typedef unsigned short u16;
typedef unsigned int   u32;
typedef unsigned char  u8;
typedef short bf16x8 __attribute__((ext_vector_type(8)));
typedef float f32x4  __attribute__((ext_vector_type(4)));
typedef float f32x2  __attribute__((ext_vector_type(2)));

// fp32 -> bf16 (RNE) bit trick
__device__ __forceinline__ u16 f2b(float f) {
    u32 u = __builtin_bit_cast(u32, f);
    u32 r = (u + 0x7FFFu + ((u >> 16) & 1u)) >> 16;
    return (u16)r;
}

// ---- hardware fp8 e4m3fn codec (gfx950 OCP; v_cvt_pk_* — 2 elems/inst) ----
__device__ __forceinline__ u8 f2q(float f) {
    return (u8)(__builtin_amdgcn_cvt_pk_fp8_f32(f, f, 0, false) & 0xFF);
}

// ======================= fused pack + init =======================
__global__ void k_pack_init(const float* __restrict__ W0, const float* __restrict__ Wl,
                            u16* __restrict__ P, int* bucketCur, float* pooled) {
    if (blockIdx.x < 32) {
        int m = blockIdx.x >> 3;                       // 0..3: W0, Wl[0..2]
        int i = (blockIdx.x & 7) * 256 + threadIdx.x;  // 0..2047
        const float* W = (m == 0) ? W0 : Wl + (size_t)(m - 1) * HF * HF;
        u16* Pm = P + (size_t)m * HF * HF;
        int lane = i & 63, kc = (i >> 6) & 3, t = i >> 8;
        int quad = lane >> 4, col = 16 * t + (lane & 15);
        #pragma unroll
        for (int j = 0; j < 8; ++j) {
            int k = kc * 32 + quad * 8 + j;
            Pm[(size_t)i * 8 + j] = f2b(W[k * HF + col]);
        }
    } else if (blockIdx.x == 32) {
        bucketCur[threadIdx.x] = threadIdx.x * BCAP;
    } else {
        pooled[(blockIdx.x - 33) * 256 + threadIdx.x] = 0.f;
    }
}

// ======================= bucketed CSR build (1024-thread wide versions) ==========
__device__ __forceinline__ void dev_bpart(int bx, const int* __restrict__ esrc,
                                          const int* __restrict__ edst,
                                          int* __restrict__ bucketCur,
                                          u32* __restrict__ epart, int ne, int ntot) {
    __shared__ int cnt[256];
    __shared__ int base[256];
    int tid = threadIdx.x;                 // 0..1023
    int t0 = bx * CH, t1 = min(t0 + CH, ntot);
    if (tid < 256) cnt[tid] = 0;
    __syncthreads();
    int sreg[2], dreg[2];
    #pragma unroll
    for (int it = 0; it < 2; ++it) {
        int t = t0 + tid + it * 1024;
        int s = 0, d = -1;
        if (t < t1) {
            if (t < ne) { s = esrc[t]; d = edst[t]; }
            else        { s = t - ne; d = s; }
            atomicAdd(&cnt[d >> 8], 1);
        }
        sreg[it] = s; dreg[it] = d;
    }
    __syncthreads();
    if (tid < 256) {
        int c = cnt[tid];
        base[tid] = c ? atomicAdd(&bucketCur[tid], c) : 0;
        cnt[tid] = 0;
    }
    __syncthreads();
    #pragma unroll
    for (int it = 0; it < 2; ++it) {
        int d = dreg[it];
        if (d >= 0) {
            int b = d >> 8;
            int pos = base[b] + atomicAdd(&cnt[b], 1);
            epart[pos] = ((u32)sreg[it] << 8) | (u32)(d & 255);
        }
    }
}

__device__ __forceinline__ void dev_bcsr(int bx, const u32* __restrict__ epart,
                                         const int* __restrict__ bucketCur,
                                         int* __restrict__ rowbeg,
                                         int* __restrict__ rowend,
                                         int* __restrict__ colidx, int n) {
    __shared__ int deg[256], offs[256], curs[256], s[256];
    int b = bx, tid = threadIdx.x;         // 0..1023
    int e0 = b * BCAP, e1 = bucketCur[b];
    if (tid < 256) { deg[tid] = 0; curs[tid] = 0; }
    __syncthreads();
    for (int t = e0 + tid; t < e1; t += 1024)
        atomicAdd(&deg[epart[t] & 255u], 1);
    __syncthreads();
    int v = 0;
    if (tid < 256) { v = deg[tid]; s[tid] = v; }
    __syncthreads();
    int acc = v;
    for (int off = 1; off < 256; off <<= 1) {
        int t = (tid < 256 && tid >= off) ? s[tid - off] : 0;
        __syncthreads();
        if (tid < 256) { acc += t; s[tid] = acc; }
        __syncthreads();
    }
    if (tid < 256) {
        int excl = acc - v;
        offs[tid] = excl;
        int node = (b << 8) + tid;
        if (node < n) {
            rowbeg[node] = e0 + excl;
            rowend[node] = e0 + excl + v;
        }
    }
    __syncthreads();
    for (int t = e0 + tid; t < e1; t += 1024) {
        u32 e = epart[t];
        int l = e & 255u;
        int pos = e0 + offs[l] + atomicAdd(&curs[l], 1);
        colidx[pos] = (int)(e >> 8);
    }
}

// ======================= MFMA GEMM (LDS-staged B, +bias, + fused alpha dots) ==========
template<bool A32, bool Q8>
__device__ __forceinline__ void dev_gemm(int rowbase, const u16* __restrict__ Ab,
                                         const float* __restrict__ Af,
                                         const u16* __restrict__ Bp,
                                         const float* __restrict__ bias,
                                         const float* __restrict__ a_s,
                                         const float* __restrict__ a_d,
                                         float* __restrict__ as_,
                                         float* __restrict__ ad_,
                                         u16* __restrict__ C,
                                         u8* __restrict__ C8, int M) {
    __shared__ u16 Bs[HF * HF];            // 32 KB packed B panel
    {
        const uint4* Bg = (const uint4*)Bp;
        uint4* Bl = (uint4*)Bs;
        for (int i = threadIdx.x; i < HF * HF / 8; i += blockDim.x)
            Bl[i] = Bg[i];
    }
    __syncthreads();

    int lane = threadIdx.x & 63;
    int wave = threadIdx.x >> 6;
    int quad = lane >> 4, l16 = lane & 15;
    int m0 = rowbase + wave * 16;
    int arow = m0 + l16;
    bool aval = arow < M;
    const bf16x8* Av = A32 ? nullptr : (const bf16x8*)(Ab + (size_t)arow * HF);
    const bf16x8* Bv = (const bf16x8*)Bs;
    f32x4 acc[8] = {};

    #pragma unroll
    for (int kc = 0; kc < 4; ++kc) {
        bf16x8 a = {};
        if (aval) {
            if constexpr (A32) {
                const float* ap = Af + (size_t)arow * HF + kc * 32 + quad * 8;
                float4 f0 = *(const float4*)ap;
                float4 f1 = *(const float4*)(ap + 4);
                a[0] = (short)f2b(f0.x); a[1] = (short)f2b(f0.y);
                a[2] = (short)f2b(f0.z); a[3] = (short)f2b(f0.w);
                a[4] = (short)f2b(f1.x); a[5] = (short)f2b(f1.y);
                a[6] = (short)f2b(f1.z); a[7] = (short)f2b(f1.w);
            } else {
                a = Av[kc * 4 + quad];
            }
        }
        #pragma unroll
        for (int t = 0; t < 8; ++t)
            acc[t] = __builtin_amdgcn_mfma_f32_16x16x32_bf16(a, Bv[t * 256 + kc * 64 + lane],
                                                             acc[t], 0, 0, 0);
    }

    int orow0 = m0 + quad * 4;
    #pragma unroll
    for (int t = 0; t < 8; ++t) {
        float b4 = bias ? bias[t * 16 + l16] : 0.f;
        #pragma unroll
        for (int r = 0; r < 4; ++r) {
            int orow = orow0 + r;
            if (orow < M) {
                float v = acc[t][r] + b4;
                if constexpr (Q8) C8[(size_t)orow * HF + t * 16 + l16] = f2q(v);
                else              C [(size_t)orow * HF + t * 16 + l16] = f2b(v);
            }
        }
    }

    if (as_) {
        float avs[8], avd[8];
        #pragma unroll
        for (int t = 0; t < 8; ++t) {
            avs[t] = a_s[t * 16 + l16];
            avd[t] = a_d[t * 16 + l16];
        }
        #pragma unroll
        for (int r = 0; r < 4; ++r) {
            float ps = 0.f, pd = 0.f;
            #pragma unroll
            for (int t = 0; t < 8; ++t) {
                ps = fmaf(acc[t][r], avs[t], ps);
                pd = fmaf(acc[t][r], avd[t], pd);
            }
            #pragma unroll
            for (int o = 1; o < 16; o <<= 1) {
                ps += __shfl_xor(ps, o);
                pd += __shfl_xor(pd, o);
            }
            int row = orow0 + r;
            if (l16 == 0 && row < M) { as_[row] = ps; ad_[row] = pd; }
        }
    }
}

// ---- merged dispatch 1 (1024 threads): wide gemm0  ||  bucket partition ----
__global__ __launch_bounds__(1024) void k_gemm0_bpart(const float* __restrict__ x,
                                                      const u16* __restrict__ Wp,
                                                      const float* __restrict__ b0,
                                                      u16* __restrict__ hb, int M, int gemmbW,
                                                      const int* __restrict__ esrc,
                                                      const int* __restrict__ edst,
                                                      int* __restrict__ bucketCur,
                                                      u32* __restrict__ epart, int ne, int ntot) {
    if ((int)blockIdx.x < gemmbW)
        dev_gemm<true, false>(blockIdx.x * 256, nullptr, x, Wp, b0,
                              nullptr, nullptr, nullptr, nullptr, hb, nullptr, M);
    else
        dev_bpart(blockIdx.x - gemmbW, esrc, edst, bucketCur, epart, ne, ntot);
}

// ---- merged dispatch 2 (1024 threads): wide layer-0 gemm  ||  bucket CSR ----
__global__ __launch_bounds__(1024) void k_gemm1_bcsr(const u16* __restrict__ hb,
                                                     const u16* __restrict__ Bp,
                                                     const float* __restrict__ a_s,
                                                     const float* __restrict__ a_d,
                                                     float* __restrict__ as_,
                                                     float* __restrict__ ad_,
                                                     u8* __restrict__ hp8, int M, int gemmbW,
                                                     const u32* __restrict__ epart,
                                                     const int* __restrict__ bucketCur,
                                                     int* __restrict__ rowbeg,
                                                     int* __restrict__ rowend,
                                                     int* __restrict__ colidx, int n) {
    if ((int)blockIdx.x < gemmbW)
        dev_gemm<false, true>(blockIdx.x * 256, hb, nullptr, Bp, nullptr,
                              a_s, a_d, as_, ad_, nullptr, hp8, M);
    else
        dev_bcsr(blockIdx.x - gemmbW, epart, bucketCur, rowbeg, rowend, colidx, n);
}

// ---- standalone layer gemm (layers 2..L): 256-thread shape ----
__global__ __launch_bounds__(256) void k_gemm_layer(const u16* __restrict__ hb,
                                                    const u16* __restrict__ Bp,
                                                    const float* __restrict__ a_s,
                                                    const float* __restrict__ a_d,
                                                    float* __restrict__ as_,
                                                    float* __restrict__ ad_,
                                                    u8* __restrict__ hp8, int M) {
    dev_gemm<false, true>(blockIdx.x * 64, hb, nullptr, Bp, nullptr,
                          a_s, a_d, as_, ad_, nullptr, hp8, M);
}

// ======================= per-dst softmax aggregation (v4: 2 nodes/wave) ==========
__device__ __forceinline__ void agg_fma4(u32 v, float w,
                                         float& a0, float& a1, float& a2, float& a3) {
    f32x2 lo = __builtin_amdgcn_cvt_pk_f32_fp8((int)v, false);
    f32x2 hi = __builtin_amdgcn_cvt_pk_f32_fp8((int)v, true);
    a0 = fmaf(w, lo.x, a0); a1 = fmaf(w, lo.y, a1);
    a2 = fmaf(w, hi.x, a2); a3 = fmaf(w, hi.y, a3);
}

template<bool POOL>
__device__ __forceinline__ void dev_agg_item(int it, const int* __restrict__ rowbeg,
                                             const int* __restrict__ rowend,
                                             const int* __restrict__ colidx,
                                             const u8* __restrict__ hp8,
                                             const float* __restrict__ as_,
                                             const float* __restrict__ ad_,
                                             const float* __restrict__ bl,
                                             u16* __restrict__ hout,
                                             int n, int relu,
                                             const int* __restrict__ batch,
                                             float* __restrict__ pooled) {
    int wv = threadIdx.x >> 6;
    int lane = threadIdx.x & 63;
    int half = lane >> 5;
    int hl = lane & 31;
    int slot = wv * 2 + half;           // node slot in block (0..7)
    int node = it * 8 + slot;
    bool valid = node < n;
    int beg = 0, end = 0;
    float adi = 0.f;
    if (valid) { beg = rowbeg[node]; end = rowend[node]; adi = ad_[node]; }
    int deg = end - beg;
    int cnt = deg < 32 ? deg : 32;
    int ecmax = cnt > 1 ? cnt - 1 : 0;

    // lane hl owns edge hl of its node (first 32)
    int srcl = (hl < deg) ? colidx[beg + hl] : 0;

    // ---- prefetch rows for edges 0..15 (needs only srcl; hides under pass 1) ----
    u32 q[16];
    int pf = cnt < 16 ? cnt : 16;
    #pragma unroll
    for (int i = 0; i < 16; ++i) {
        int ec = i < cnt ? i : ecmax;
        int s = __shfl(srcl, ec, 32);
        if (i < pf) q[i] = ((const u32*)(hp8 + (size_t)s * HF))[hl];
    }

    // ---- pass 1: exp weights (no max-sub), 32-lane sum reduce ----
    float el = 0.f;
    if (hl < deg) {
        float e = as_[srcl] + adi;
        e = e > 0.f ? e : NEG * e;
        el = __expf(e);
    }
    float ssum = el;
    for (int jj = beg + 32 + hl; jj < end; jj += 32) {
        float e = as_[colidx[jj]] + adi;
        e = e > 0.f ? e : NEG * e;
        ssum += __expf(e);
    }
    #pragma unroll
    for (int off = 16; off; off >>= 1) ssum += __shfl_xor(ssum, off, 32);
    float wl = el;              // UNNORMALIZED edge weight (1/sum in epilogue)

    // ---- pass 2: consume prefetched edges ----
    float a0 = 0.f, a1 = 0.f, a2 = 0.f, a3 = 0.f;
    #pragma unroll
    for (int i = 0; i < 16; ++i) {
        float w = (i < cnt) ? __shfl(wl, i, 32) : 0.f;
        if (i < pf) agg_fma4(q[i], w, a0, a1, a2, a3);
    }
    // remainder edges 16..cnt-1: batched 8-at-a-time (loads independent)
    for (int base = 16; base < cnt; base += 8) {
        u32 r[8];
        int mrem = cnt - base < 8 ? cnt - base : 8;
        #pragma unroll
        for (int i = 0; i < 8; ++i) {
            int ec = base + i < cnt ? base + i : ecmax;
            int s = __shfl(srcl, ec, 32);
            if (i < mrem) r[i] = ((const u32*)(hp8 + (size_t)s * HF))[hl];
        }
        #pragma unroll
        for (int i = 0; i < 8; ++i) {
            if (i < mrem) {
                float w = __shfl(wl, base + i, 32);
                agg_fma4(r[i], w, a0, a1, a2, a3);
            }
        }
    }
    // rare deg>32 tail: all 32 lanes of the half, uniform weight per edge
    for (int jj = beg + 32; jj < end; ++jj) {
        int s = colidx[jj];
        float e = as_[s] + adi;
        e = e > 0.f ? e : NEG * e;
        float w = __expf(e);
        u32 v = ((const u32*)(hp8 + (size_t)s * HF))[hl];
        agg_fma4(v, w, a0, a1, a2, a3);
    }

    if constexpr (!POOL) {
        if (valid) {
            float inv = 1.f / ssum;
            float4 bb = ((const float4*)bl)[hl];
            a0 = fmaf(a0, inv, bb.x); a1 = fmaf(a1, inv, bb.y);
            a2 = fmaf(a2, inv, bb.z); a3 = fmaf(a3, inv, bb.w);
            if (relu) {
                a0 = fmaxf(a0, 0.f); a1 = fmaxf(a1, 0.f);
                a2 = fmaxf(a2, 0.f); a3 = fmaxf(a3, 0.f);
            }
            uint2 o;
            o.x = ((u32)f2b(a1) << 16) | (u32)f2b(a0);
            o.y = ((u32)f2b(a3) << 16) | (u32)f2b(a2);
            ((uint2*)(hout + (size_t)node * HF))[hl] = o;
        }
    } else {
        __shared__ float ptile[8][HF];
        {
            float inv = valid ? 1.f / ssum : 0.f;
            float4 bb = ((const float4*)bl)[hl];
            ptile[slot][hl * 4 + 0] = valid ? fmaf(a0, inv, bb.x) : 0.f;
            ptile[slot][hl * 4 + 1] = valid ? fmaf(a1, inv, bb.y) : 0.f;
            ptile[slot][hl * 4 + 2] = valid ? fmaf(a2, inv, bb.z) : 0.f;
            ptile[slot][hl * 4 + 3] = valid ? fmaf(a3, inv, bb.w) : 0.f;
        }
        __syncthreads();
        int tid = threadIdx.x;
        if (tid < HF) {
            float a = 0.f;
            int curb = -1;
            #pragma unroll
            for (int s2 = 0; s2 < 8; ++s2) {
                int nd = it * 8 + s2;
                if (nd < n) {
                    int b = batch[nd];
                    if (b != curb) {
                        if (curb >= 0) atomicAdd(&pooled[curb * HF + tid], a);
                        curb = b;
                        a = 0.f;
                    }
                    a += ptile[s2][tid];
                }
            }
            if (curb >= 0) atomicAdd(&pooled[curb * HF + tid], a);
        }
    }
}

__global__ __launch_bounds__(256) void k_agg(const int* __restrict__ rowbeg,
                                             const int* __restrict__ rowend,
                                             const int* __restrict__ colidx,
                                             const u8* __restrict__ hp8,
                                             const float* __restrict__ as_,
                                             const float* __restrict__ ad_,
                                             const float* __restrict__ bl,
                                             u16* __restrict__ hout,
                                             int n, int relu) {
    dev_agg_item<false>(blockIdx.x, rowbeg, rowend, colidx, hp8, as_, ad_, bl,
                        hout, n, relu, nullptr, nullptr);
}

// final layer: agg (no relu) + fused global_add_pool
__global__ __launch_bounds__(256) void k_agg_pool(const int* __restrict__ rowbeg,
                                                  const int* __restrict__ rowend,
                                                  const int* __restrict__ colidx,
                                                  const u8* __restrict__ hp8,
                                                  const float* __restrict__ as_,
                                                  const float* __restrict__ ad_,
                                                  const float* __restrict__ bl,
                                                  int n,
                                                  const int* __restrict__ batch,
                                                  float* __restrict__ pooled) {
    dev_agg_item<true>(blockIdx.x, rowbeg, rowend, colidx, hp8, as_, ad_, bl,
                       nullptr, n, 0, batch, pooled);
}

__global__ void k_final(const float* __restrict__ pooled, const float* __restrict__ Wf,
                        const float* __restrict__ bf, float* __restrict__ out) {
    int g = blockIdx.x, o = threadIdx.x;   // 64 threads
    float acc = bf[o];
    #pragma unroll 8
    for (int k = 0; k < HF; ++k) acc = fmaf(pooled[g * HF + k], Wf[k * OUTF + o], acc);
    out[g * OUTF + o] = acc;
}

// ======================= launch =======================
extern "C" void kernel_launch(void* const* d_in, const int* in_sizes, int n_in,
                              void* d_out, int out_size, void* d_ws, size_t ws_size,
                              hipStream_t stream) {
    const float* x      = (const float*)d_in[0];
    const int*   edge   = (const int*)d_in[1];
    const int*   batch  = (const int*)d_in[2];
    const float* W0     = (const float*)d_in[3];
    const float* b0     = (const float*)d_in[4];
    const float* Wl     = (const float*)d_in[5];
    const float* a_src  = (const float*)d_in[6];
    const float* a_dst  = (const float*)d_in[7];
    const float* bl     = (const float*)d_in[8];
    const float* Wf     = (const float*)d_in[9];
    const float* bf     = (const float*)d_in[10];
    float* out = (float*)d_out;

    const int N  = in_sizes[2];
    const int E  = in_sizes[1] / 2;
    const int Et = E + N;
    const int L  = 3;
    const int NB = (N + 255) >> 8;               // buckets (<= 256)

    char* ws = (char*)d_ws;
    size_t off = 0;
    auto alloc = [&](size_t bytes) { char* p = ws + off; off += (bytes + 255) & ~(size_t)255; return p; };
    u16*   hb      = (u16*)alloc((size_t)N * HF * 2);
    u8*    hp8     = (u8*)alloc((size_t)N * HF);
    u16*   Wp      = (u16*)alloc((size_t)4 * HF * HF * 2);
    float* as_     = (float*)alloc((size_t)N * 4);
    float* ad_     = (float*)alloc((size_t)N * 4);
    int*   rowbeg  = (int*)alloc((size_t)N * 4);
    int*   rowend  = (int*)alloc((size_t)N * 4);
    int*   colidx  = (int*)alloc((size_t)NB * BCAP * 4);
    u32*   epart   = (u32*)alloc((size_t)NB * BCAP * 4);
    int*   bucketCur = (int*)alloc(256 * 4);
    float* pooled  = (float*)alloc((size_t)GCOUNT * HF * 4);
    (void)ws_size; (void)n_in; (void)out_size;

    const int wb8    = (N + 7) / 8;              // agg kernels: 8 nodes/block
    const int gemmb  = (N + 63) / 64;            // 256-thread gemms
    const int gemmbW = (N + 255) / 256;          // 1024-thread wide gemms
    const int partb  = (Et + CH - 1) / CH;

    const int* esrc = edge;
    const int* edst = edge + E;

    // --- pack weights + init bucketCur + zero pooled (one launch) ---
    k_pack_init<<<65, 256, 0, stream>>>(W0, Wl, Wp, bucketCur, pooled);

    // --- wide gemm0 (x @ W0 + b0)  ||  bucket partition (1024-thread blocks) ---
    k_gemm0_bpart<<<gemmbW + partb, 1024, 0, stream>>>(x, Wp, b0, hb, N, gemmbW,
                                                       esrc, edst, bucketCur, epart, E, Et);

    // --- wide layer-0 gemm (+dots, fp8 out)  ||  bucket CSR (1024-thread blocks) ---
    k_gemm1_bcsr<<<gemmbW + NB, 1024, 0, stream>>>(hb, Wp + (size_t)1 * HF * HF,
                                                   a_src, a_dst, as_, ad_, hp8, N, gemmbW,
                                                   epart, bucketCur, rowbeg, rowend, colidx, N);

    // ===== MEASUREMENT (this round only): amplify merged dispatch 2 x16 =====
    // Both sides are idempotent: gemm1 reads hb/Wp/a_*, deterministically
    // overwrites hp8/as_/ad_; bcsr reads epart/bucketCur (read-only here),
    // deterministically overwrites rowbeg/rowend/colidx. Result bit-identical.
    // t_merged2 = (dur - 228.3)/16.
    for (int rep = 0; rep < 16; ++rep)
        k_gemm1_bcsr<<<gemmbW + NB, 1024, 0, stream>>>(hb, Wp + (size_t)1 * HF * HF,
                                                       a_src, a_dst, as_, ad_, hp8, N, gemmbW,
                                                       epart, bucketCur, rowbeg, rowend, colidx, N);

    // --- GAT layers; final layer fuses global_add_pool ---
    for (int l = 0; l < L; ++l) {
        if (l > 0)
            k_gemm_layer<<<gemmb, 256, 0, stream>>>(hb, Wp + (size_t)(l + 1) * HF * HF,
                                                    a_src + l * HF, a_dst + l * HF,
                                                    as_, ad_, hp8, N);
        if (l < L - 1)
            k_agg<<<wb8, 256, 0, stream>>>(rowbeg, rowend, colidx, hp8, as_, ad_,
                                           bl + l * HF, hb, N, 1);
        else
            k_agg_pool<<<wb8, 256, 0, stream>>>(rowbeg, rowend, colidx, hp8, as_, ad_,
                                                bl + l * HF, N, batch, pooled);
    }

    // --- final linear ---
    k_final<<<GCOUNT, OUTF, 0, stream>>>(pooled, Wf, bf, out);
}

// Round 13
// 235.818 us; speedup vs baseline: 1.8922x; 1.8922x over previous
//
#include <hip/hip_runtime.h>
#include <hip/hip_bf16.h>
#include <math.h>

#define HF 128          // hidden / input feature dim
#define GCOUNT 64       // graphs in batch
#define OUTF 64         // final output features
#define NEG 0.2f        // leaky relu slope
#define CH 2048         // edges per partition block
#define BCAP 8192       // per-bucket edge capacity (expected ~4340, +50 sigma)

typedef unsigned short u16;
typedef unsigned int   u32;
typedef unsigned char  u8;
typedef short bf16x8 __attribute__((ext_vector_type(8)));
typedef float f32x4  __attribute__((ext_vector_type(4)));
typedef float f32x2  __attribute__((ext_vector_type(2)));

// fp32 -> bf16 (RNE) bit trick
__device__ __forceinline__ u16 f2b(float f) {
    u32 u = __builtin_bit_cast(u32, f);
    u32 r = (u + 0x7FFFu + ((u >> 16) & 1u)) >> 16;
    return (u16)r;
}

// ---- hardware fp8 e4m3fn codec (gfx950 OCP; v_cvt_pk_* — 2 elems/inst) ----
__device__ __forceinline__ u8 f2q(float f) {
    return (u8)(__builtin_amdgcn_cvt_pk_fp8_f32(f, f, 0, false) & 0xFF);
}

// ======================= weight pack (32 blocks; bucketCur/pooled now memset) ==========
__global__ void k_pack(const float* __restrict__ W0, const float* __restrict__ Wl,
                       u16* __restrict__ P) {
    int m = blockIdx.x >> 3;                       // 0..3: W0, Wl[0..2]
    int i = (blockIdx.x & 7) * 256 + threadIdx.x;  // 0..2047
    const float* W = (m == 0) ? W0 : Wl + (size_t)(m - 1) * HF * HF;
    u16* Pm = P + (size_t)m * HF * HF;
    int lane = i & 63, kc = (i >> 6) & 3, t = i >> 8;
    int quad = lane >> 4, col = 16 * t + (lane & 15);
    #pragma unroll
    for (int j = 0; j < 8; ++j) {
        int k = kc * 32 + quad * 8 + j;
        Pm[(size_t)i * 8 + j] = f2b(W[k * HF + col]);
    }
}

// ======================= bucketed CSR build (1024-thread, zero-based counters) ==========
// bucketCur[b] is zero-initialized (hipMemsetAsync); holds bucket b's edge count.
// Absolute positions are b*BCAP + relative offset.
__device__ __forceinline__ void dev_bpart(int bx, const int* __restrict__ esrc,
                                          const int* __restrict__ edst,
                                          int* __restrict__ bucketCur,
                                          u32* __restrict__ epart, int ne, int ntot) {
    __shared__ int cnt[256];
    __shared__ int base[256];
    int tid = threadIdx.x;                 // 0..1023
    int t0 = bx * CH, t1 = min(t0 + CH, ntot);
    if (tid < 256) cnt[tid] = 0;
    __syncthreads();
    int sreg[2], dreg[2];
    #pragma unroll
    for (int it = 0; it < 2; ++it) {
        int t = t0 + tid + it * 1024;
        int s = 0, d = -1;
        if (t < t1) {
            if (t < ne) { s = esrc[t]; d = edst[t]; }
            else        { s = t - ne; d = s; }
            atomicAdd(&cnt[d >> 8], 1);
        }
        sreg[it] = s; dreg[it] = d;
    }
    __syncthreads();
    if (tid < 256) {
        int c = cnt[tid];
        base[tid] = c ? atomicAdd(&bucketCur[tid], c) : 0;   // relative base
        cnt[tid] = 0;
    }
    __syncthreads();
    #pragma unroll
    for (int it = 0; it < 2; ++it) {
        int d = dreg[it];
        if (d >= 0) {
            int b = d >> 8;
            int pos = b * BCAP + base[b] + atomicAdd(&cnt[b], 1);
            epart[pos] = ((u32)sreg[it] << 8) | (u32)(d & 255);
        }
    }
}

__device__ __forceinline__ void dev_bcsr(int bx, const u32* __restrict__ epart,
                                         const int* __restrict__ bucketCur,
                                         int* __restrict__ rowbeg,
                                         int* __restrict__ rowend,
                                         int* __restrict__ colidx, int n) {
    __shared__ int deg[256], offs[256], curs[256], s[256];
    int b = bx, tid = threadIdx.x;         // 0..1023
    int e0 = b * BCAP, e1 = e0 + bucketCur[b];
    if (tid < 256) { deg[tid] = 0; curs[tid] = 0; }
    __syncthreads();
    for (int t = e0 + tid; t < e1; t += 1024)
        atomicAdd(&deg[epart[t] & 255u], 1);
    __syncthreads();
    int v = 0;
    if (tid < 256) { v = deg[tid]; s[tid] = v; }
    __syncthreads();
    int acc = v;
    for (int off = 1; off < 256; off <<= 1) {
        int t = (tid < 256 && tid >= off) ? s[tid - off] : 0;
        __syncthreads();
        if (tid < 256) { acc += t; s[tid] = acc; }
        __syncthreads();
    }
    if (tid < 256) {
        int excl = acc - v;
        offs[tid] = excl;
        int node = (b << 8) + tid;
        if (node < n) {
            rowbeg[node] = e0 + excl;
            rowend[node] = e0 + excl + v;
        }
    }
    __syncthreads();
    for (int t = e0 + tid; t < e1; t += 1024) {
        u32 e = epart[t];
        int l = e & 255u;
        int pos = e0 + offs[l] + atomicAdd(&curs[l], 1);
        colidx[pos] = (int)(e >> 8);
    }
}

// ======================= MFMA GEMM (LDS-staged B, +bias, + fused alpha dots) ==========
template<bool A32, bool Q8>
__device__ __forceinline__ void dev_gemm(int rowbase, const u16* __restrict__ Ab,
                                         const float* __restrict__ Af,
                                         const u16* __restrict__ Bp,
                                         const float* __restrict__ bias,
                                         const float* __restrict__ a_s,
                                         const float* __restrict__ a_d,
                                         float* __restrict__ as_,
                                         float* __restrict__ ad_,
                                         u16* __restrict__ C,
                                         u8* __restrict__ C8, int M) {
    __shared__ u16 Bs[HF * HF];            // 32 KB packed B panel
    {
        const uint4* Bg = (const uint4*)Bp;
        uint4* Bl = (uint4*)Bs;
        for (int i = threadIdx.x; i < HF * HF / 8; i += blockDim.x)
            Bl[i] = Bg[i];
    }
    __syncthreads();

    int lane = threadIdx.x & 63;
    int wave = threadIdx.x >> 6;
    int quad = lane >> 4, l16 = lane & 15;
    int m0 = rowbase + wave * 16;
    int arow = m0 + l16;
    bool aval = arow < M;
    const bf16x8* Av = A32 ? nullptr : (const bf16x8*)(Ab + (size_t)arow * HF);
    const bf16x8* Bv = (const bf16x8*)Bs;
    f32x4 acc[8] = {};

    #pragma unroll
    for (int kc = 0; kc < 4; ++kc) {
        bf16x8 a = {};
        if (aval) {
            if constexpr (A32) {
                const float* ap = Af + (size_t)arow * HF + kc * 32 + quad * 8;
                float4 f0 = *(const float4*)ap;
                float4 f1 = *(const float4*)(ap + 4);
                a[0] = (short)f2b(f0.x); a[1] = (short)f2b(f0.y);
                a[2] = (short)f2b(f0.z); a[3] = (short)f2b(f0.w);
                a[4] = (short)f2b(f1.x); a[5] = (short)f2b(f1.y);
                a[6] = (short)f2b(f1.z); a[7] = (short)f2b(f1.w);
            } else {
                a = Av[kc * 4 + quad];
            }
        }
        #pragma unroll
        for (int t = 0; t < 8; ++t)
            acc[t] = __builtin_amdgcn_mfma_f32_16x16x32_bf16(a, Bv[t * 256 + kc * 64 + lane],
                                                             acc[t], 0, 0, 0);
    }

    int orow0 = m0 + quad * 4;
    #pragma unroll
    for (int t = 0; t < 8; ++t) {
        float b4 = bias ? bias[t * 16 + l16] : 0.f;
        #pragma unroll
        for (int r = 0; r < 4; ++r) {
            int orow = orow0 + r;
            if (orow < M) {
                float v = acc[t][r] + b4;
                if constexpr (Q8) C8[(size_t)orow * HF + t * 16 + l16] = f2q(v);
                else              C [(size_t)orow * HF + t * 16 + l16] = f2b(v);
            }
        }
    }

    if (as_) {
        float avs[8], avd[8];
        #pragma unroll
        for (int t = 0; t < 8; ++t) {
            avs[t] = a_s[t * 16 + l16];
            avd[t] = a_d[t * 16 + l16];
        }
        #pragma unroll
        for (int r = 0; r < 4; ++r) {
            float ps = 0.f, pd = 0.f;
            #pragma unroll
            for (int t = 0; t < 8; ++t) {
                ps = fmaf(acc[t][r], avs[t], ps);
                pd = fmaf(acc[t][r], avd[t], pd);
            }
            #pragma unroll
            for (int o = 1; o < 16; o <<= 1) {
                ps += __shfl_xor(ps, o);
                pd += __shfl_xor(pd, o);
            }
            int row = orow0 + r;
            if (l16 == 0 && row < M) { as_[row] = ps; ad_[row] = pd; }
        }
    }
}

// ---- merged dispatch 1 (1024 threads): wide gemm0  ||  bucket partition ----
__global__ __launch_bounds__(1024) void k_gemm0_bpart(const float* __restrict__ x,
                                                      const u16* __restrict__ Wp,
                                                      const float* __restrict__ b0,
                                                      u16* __restrict__ hb, int M, int gemmbW,
                                                      const int* __restrict__ esrc,
                                                      const int* __restrict__ edst,
                                                      int* __restrict__ bucketCur,
                                                      u32* __restrict__ epart, int ne, int ntot) {
    if ((int)blockIdx.x < gemmbW)
        dev_gemm<true, false>(blockIdx.x * 256, nullptr, x, Wp, b0,
                              nullptr, nullptr, nullptr, nullptr, hb, nullptr, M);
    else
        dev_bpart(blockIdx.x - gemmbW, esrc, edst, bucketCur, epart, ne, ntot);
}

// ---- merged dispatch 2 (1024 threads): wide layer-0 gemm  ||  bucket CSR ----
__global__ __launch_bounds__(1024) void k_gemm1_bcsr(const u16* __restrict__ hb,
                                                     const u16* __restrict__ Bp,
                                                     const float* __restrict__ a_s,
                                                     const float* __restrict__ a_d,
                                                     float* __restrict__ as_,
                                                     float* __restrict__ ad_,
                                                     u8* __restrict__ hp8, int M, int gemmbW,
                                                     const u32* __restrict__ epart,
                                                     const int* __restrict__ bucketCur,
                                                     int* __restrict__ rowbeg,
                                                     int* __restrict__ rowend,
                                                     int* __restrict__ colidx, int n) {
    if ((int)blockIdx.x < gemmbW)
        dev_gemm<false, true>(blockIdx.x * 256, hb, nullptr, Bp, nullptr,
                              a_s, a_d, as_, ad_, nullptr, hp8, M);
    else
        dev_bcsr(blockIdx.x - gemmbW, epart, bucketCur, rowbeg, rowend, colidx, n);
}

// ---- standalone layer gemm (layers 2..L): 256-thread shape ----
__global__ __launch_bounds__(256) void k_gemm_layer(const u16* __restrict__ hb,
                                                    const u16* __restrict__ Bp,
                                                    const float* __restrict__ a_s,
                                                    const float* __restrict__ a_d,
                                                    float* __restrict__ as_,
                                                    float* __restrict__ ad_,
                                                    u8* __restrict__ hp8, int M) {
    dev_gemm<false, true>(blockIdx.x * 64, hb, nullptr, Bp, nullptr,
                          a_s, a_d, as_, ad_, nullptr, hp8, M);
}

// ======================= per-dst softmax aggregation (v4: 2 nodes/wave) ==========
__device__ __forceinline__ void agg_fma4(u32 v, float w,
                                         float& a0, float& a1, float& a2, float& a3) {
    f32x2 lo = __builtin_amdgcn_cvt_pk_f32_fp8((int)v, false);
    f32x2 hi = __builtin_amdgcn_cvt_pk_f32_fp8((int)v, true);
    a0 = fmaf(w, lo.x, a0); a1 = fmaf(w, lo.y, a1);
    a2 = fmaf(w, hi.x, a2); a3 = fmaf(w, hi.y, a3);
}

template<bool POOL>
__device__ __forceinline__ void dev_agg_item(int it, const int* __restrict__ rowbeg,
                                             const int* __restrict__ rowend,
                                             const int* __restrict__ colidx,
                                             const u8* __restrict__ hp8,
                                             const float* __restrict__ as_,
                                             const float* __restrict__ ad_,
                                             const float* __restrict__ bl,
                                             u16* __restrict__ hout,
                                             int n, int relu,
                                             const int* __restrict__ batch,
                                             float* __restrict__ pooled) {
    int wv = threadIdx.x >> 6;
    int lane = threadIdx.x & 63;
    int half = lane >> 5;
    int hl = lane & 31;
    int slot = wv * 2 + half;           // node slot in block (0..7)
    int node = it * 8 + slot;
    bool valid = node < n;
    int beg = 0, end = 0;
    float adi = 0.f;
    if (valid) { beg = rowbeg[node]; end = rowend[node]; adi = ad_[node]; }
    int deg = end - beg;
    int cnt = deg < 32 ? deg : 32;
    int ecmax = cnt > 1 ? cnt - 1 : 0;

    // lane hl owns edge hl of its node (first 32)
    int srcl = (hl < deg) ? colidx[beg + hl] : 0;

    // ---- prefetch rows for edges 0..15 (needs only srcl; hides under pass 1) ----
    u32 q[16];
    int pf = cnt < 16 ? cnt : 16;
    #pragma unroll
    for (int i = 0; i < 16; ++i) {
        int ec = i < cnt ? i : ecmax;
        int s = __shfl(srcl, ec, 32);
        if (i < pf) q[i] = ((const u32*)(hp8 + (size_t)s * HF))[hl];
    }

    // ---- pass 1: exp weights (no max-sub), 32-lane sum reduce ----
    float el = 0.f;
    if (hl < deg) {
        float e = as_[srcl] + adi;
        e = e > 0.f ? e : NEG * e;
        el = __expf(e);
    }
    float ssum = el;
    for (int jj = beg + 32 + hl; jj < end; jj += 32) {
        float e = as_[colidx[jj]] + adi;
        e = e > 0.f ? e : NEG * e;
        ssum += __expf(e);
    }
    #pragma unroll
    for (int off = 16; off; off >>= 1) ssum += __shfl_xor(ssum, off, 32);
    float wl = el;              // UNNORMALIZED edge weight (1/sum in epilogue)

    // ---- pass 2: consume prefetched edges ----
    float a0 = 0.f, a1 = 0.f, a2 = 0.f, a3 = 0.f;
    #pragma unroll
    for (int i = 0; i < 16; ++i) {
        float w = (i < cnt) ? __shfl(wl, i, 32) : 0.f;
        if (i < pf) agg_fma4(q[i], w, a0, a1, a2, a3);
    }
    // remainder edges 16..cnt-1: batched 8-at-a-time (loads independent)
    for (int base = 16; base < cnt; base += 8) {
        u32 r[8];
        int mrem = cnt - base < 8 ? cnt - base : 8;
        #pragma unroll
        for (int i = 0; i < 8; ++i) {
            int ec = base + i < cnt ? base + i : ecmax;
            int s = __shfl(srcl, ec, 32);
            if (i < mrem) r[i] = ((const u32*)(hp8 + (size_t)s * HF))[hl];
        }
        #pragma unroll
        for (int i = 0; i < 8; ++i) {
            if (i < mrem) {
                float w = __shfl(wl, base + i, 32);
                agg_fma4(r[i], w, a0, a1, a2, a3);
            }
        }
    }
    // rare deg>32 tail: all 32 lanes of the half, uniform weight per edge
    for (int jj = beg + 32; jj < end; ++jj) {
        int s = colidx[jj];
        float e = as_[s] + adi;
        e = e > 0.f ? e : NEG * e;
        float w = __expf(e);
        u32 v = ((const u32*)(hp8 + (size_t)s * HF))[hl];
        agg_fma4(v, w, a0, a1, a2, a3);
    }

    if constexpr (!POOL) {
        if (valid) {
            float inv = 1.f / ssum;
            float4 bb = ((const float4*)bl)[hl];
            a0 = fmaf(a0, inv, bb.x); a1 = fmaf(a1, inv, bb.y);
            a2 = fmaf(a2, inv, bb.z); a3 = fmaf(a3, inv, bb.w);
            if (relu) {
                a0 = fmaxf(a0, 0.f); a1 = fmaxf(a1, 0.f);
                a2 = fmaxf(a2, 0.f); a3 = fmaxf(a3, 0.f);
            }
            uint2 o;
            o.x = ((u32)f2b(a1) << 16) | (u32)f2b(a0);
            o.y = ((u32)f2b(a3) << 16) | (u32)f2b(a2);
            ((uint2*)(hout + (size_t)node * HF))[hl] = o;
        }
    } else {
        __shared__ float ptile[8][HF];
        {
            float inv = valid ? 1.f / ssum : 0.f;
            float4 bb = ((const float4*)bl)[hl];
            ptile[slot][hl * 4 + 0] = valid ? fmaf(a0, inv, bb.x) : 0.f;
            ptile[slot][hl * 4 + 1] = valid ? fmaf(a1, inv, bb.y) : 0.f;
            ptile[slot][hl * 4 + 2] = valid ? fmaf(a2, inv, bb.z) : 0.f;
            ptile[slot][hl * 4 + 3] = valid ? fmaf(a3, inv, bb.w) : 0.f;
        }
        __syncthreads();
        int tid = threadIdx.x;
        if (tid < HF) {
            float a = 0.f;
            int curb = -1;
            #pragma unroll
            for (int s2 = 0; s2 < 8; ++s2) {
                int nd = it * 8 + s2;
                if (nd < n) {
                    int b = batch[nd];
                    if (b != curb) {
                        if (curb >= 0) atomicAdd(&pooled[curb * HF + tid], a);
                        curb = b;
                        a = 0.f;
                    }
                    a += ptile[s2][tid];
                }
            }
            if (curb >= 0) atomicAdd(&pooled[curb * HF + tid], a);
        }
    }
}

__global__ __launch_bounds__(256) void k_agg(const int* __restrict__ rowbeg,
                                             const int* __restrict__ rowend,
                                             const int* __restrict__ colidx,
                                             const u8* __restrict__ hp8,
                                             const float* __restrict__ as_,
                                             const float* __restrict__ ad_,
                                             const float* __restrict__ bl,
                                             u16* __restrict__ hout,
                                             int n, int relu) {
    dev_agg_item<false>(blockIdx.x, rowbeg, rowend, colidx, hp8, as_, ad_, bl,
                        hout, n, relu, nullptr, nullptr);
}

// final layer: agg (no relu) + fused global_add_pool
__global__ __launch_bounds__(256) void k_agg_pool(const int* __restrict__ rowbeg,
                                                  const int* __restrict__ rowend,
                                                  const int* __restrict__ colidx,
                                                  const u8* __restrict__ hp8,
                                                  const float* __restrict__ as_,
                                                  const float* __restrict__ ad_,
                                                  const float* __restrict__ bl,
                                                  int n,
                                                  const int* __restrict__ batch,
                                                  float* __restrict__ pooled) {
    dev_agg_item<true>(blockIdx.x, rowbeg, rowend, colidx, hp8, as_, ad_, bl,
                       nullptr, n, 0, batch, pooled);
}

__global__ void k_final(const float* __restrict__ pooled, const float* __restrict__ Wf,
                        const float* __restrict__ bf, float* __restrict__ out) {
    int g = blockIdx.x, o = threadIdx.x;   // 64 threads
    float acc = bf[o];
    #pragma unroll 8
    for (int k = 0; k < HF; ++k) acc = fmaf(pooled[g * HF + k], Wf[k * OUTF + o], acc);
    out[g * OUTF + o] = acc;
}

// ======================= launch =======================
extern "C" void kernel_launch(void* const* d_in, const int* in_sizes, int n_in,
                              void* d_out, int out_size, void* d_ws, size_t ws_size,
                              hipStream_t stream) {
    const float* x      = (const float*)d_in[0];
    const int*   edge   = (const int*)d_in[1];
    const int*   batch  = (const int*)d_in[2];
    const float* W0     = (const float*)d_in[3];
    const float* b0     = (const float*)d_in[4];
    const float* Wl     = (const float*)d_in[5];
    const float* a_src  = (const float*)d_in[6];
    const float* a_dst  = (const float*)d_in[7];
    const float* bl     = (const float*)d_in[8];
    const float* Wf     = (const float*)d_in[9];
    const float* bf     = (const float*)d_in[10];
    float* out = (float*)d_out;

    const int N  = in_sizes[2];
    const int E  = in_sizes[1] / 2;
    const int Et = E + N;
    const int L  = 3;
    const int NB = (N + 255) >> 8;               // buckets (<= 256)

    char* ws = (char*)d_ws;
    size_t off = 0;
    auto alloc = [&](size_t bytes) { char* p = ws + off; off += (bytes + 255) & ~(size_t)255; return p; };
    u16*   hb      = (u16*)alloc((size_t)N * HF * 2);
    u8*    hp8     = (u8*)alloc((size_t)N * HF);
    u16*   Wp      = (u16*)alloc((size_t)4 * HF * HF * 2);
    float* as_     = (float*)alloc((size_t)N * 4);
    float* ad_     = (float*)alloc((size_t)N * 4);
    int*   rowbeg  = (int*)alloc((size_t)N * 4);
    int*   rowend  = (int*)alloc((size_t)N * 4);
    int*   colidx  = (int*)alloc((size_t)NB * BCAP * 4);
    u32*   epart   = (u32*)alloc((size_t)NB * BCAP * 4);
    int*   bucketCur = (int*)alloc(256 * 4);
    float* pooled  = (float*)alloc((size_t)GCOUNT * HF * 4);
    (void)ws_size; (void)n_in; (void)out_size;

    const int wb8    = (N + 7) / 8;              // agg kernels: 8 nodes/block
    const int gemmb  = (N + 63) / 64;            // 256-thread gemms
    const int gemmbW = (N + 255) / 256;          // 1024-thread wide gemms
    const int partb  = (Et + CH - 1) / CH;

    const int* esrc = edge;
    const int* edst = edge + E;

    // --- zero bucketCur + pooled (stream memsets, capture-safe) + pack weights ---
    hipMemsetAsync(bucketCur, 0, 256 * 4, stream);
    hipMemsetAsync(pooled, 0, (size_t)GCOUNT * HF * 4, stream);
    k_pack<<<32, 256, 0, stream>>>(W0, Wl, Wp);

    // --- wide gemm0 (x @ W0 + b0)  ||  bucket partition (1024-thread blocks) ---
    k_gemm0_bpart<<<gemmbW + partb, 1024, 0, stream>>>(x, Wp, b0, hb, N, gemmbW,
                                                       esrc, edst, bucketCur, epart, E, Et);

    // --- wide layer-0 gemm (+dots, fp8 out)  ||  bucket CSR (1024-thread blocks) ---
    k_gemm1_bcsr<<<gemmbW + NB, 1024, 0, stream>>>(hb, Wp + (size_t)1 * HF * HF,
                                                   a_src, a_dst, as_, ad_, hp8, N, gemmbW,
                                                   epart, bucketCur, rowbeg, rowend, colidx, N);

    // --- GAT layers; final layer fuses global_add_pool ---
    for (int l = 0; l < L; ++l) {
        if (l > 0)
            k_gemm_layer<<<gemmb, 256, 0, stream>>>(hb, Wp + (size_t)(l + 1) * HF * HF,
                                                    a_src + l * HF, a_dst + l * HF,
                                                    as_, ad_, hp8, N);
        if (l < L - 1)
            k_agg<<<wb8, 256, 0, stream>>>(rowbeg, rowend, colidx, hp8, as_, ad_,
                                           bl + l * HF, hb, N, 1);
        else
            k_agg_pool<<<wb8, 256, 0, stream>>>(rowbeg, rowend, colidx, hp8, as_, ad_,
                                                bl + l * HF, N, batch, pooled);
    }

    // --- final linear ---
    k_final<<<GCOUNT, OUTF, 0, stream>>>(pooled, Wf, bf, out);
}

// Round 14
// 227.820 us; speedup vs baseline: 1.9586x; 1.0351x over previous
//
#include <hip/hip_runtime.h>
#include <hip/hip_bf16.h>
#include <math.h>

#define HF 128          // hidden / input feature dim
#define GCOUNT 64       // graphs in batch
#define OUTF 64         // final output features
#define NEG 0.2f        // leaky relu slope
#define CH 2048         // edges per partition block
#define BCAP 8192       // per-bucket edge capacity (expected ~4340, +50 sigma)

typedef unsigned short u16;
typedef unsigned int   u32;
typedef unsigned char  u8;
typedef short bf16x8 __attribute__((ext_vector_type(8)));
typedef float f32x4  __attribute__((ext_vector_type(4)));
typedef float f32x2  __attribute__((ext_vector_type(2)));

// fp32 -> bf16 (RNE) bit trick
__device__ __forceinline__ u16 f2b(float f) {
    u32 u = __builtin_bit_cast(u32, f);
    u32 r = (u + 0x7FFFu + ((u >> 16) & 1u)) >> 16;
    return (u16)r;
}

// ---- hardware fp8 e4m3fn codec (gfx950 OCP; v_cvt_pk_* — 2 elems/inst) ----
__device__ __forceinline__ u8 f2q(float f) {
    return (u8)(__builtin_amdgcn_cvt_pk_fp8_f32(f, f, 0, false) & 0xFF);
}

// ======================= fused pack + init =======================
__global__ void k_pack_init(const float* __restrict__ W0, const float* __restrict__ Wl,
                            u16* __restrict__ P, int* bucketCur, float* pooled) {
    if (blockIdx.x < 32) {
        int m = blockIdx.x >> 3;                       // 0..3: W0, Wl[0..2]
        int i = (blockIdx.x & 7) * 256 + threadIdx.x;  // 0..2047
        const float* W = (m == 0) ? W0 : Wl + (size_t)(m - 1) * HF * HF;
        u16* Pm = P + (size_t)m * HF * HF;
        int lane = i & 63, kc = (i >> 6) & 3, t = i >> 8;
        int quad = lane >> 4, col = 16 * t + (lane & 15);
        #pragma unroll
        for (int j = 0; j < 8; ++j) {
            int k = kc * 32 + quad * 8 + j;
            Pm[(size_t)i * 8 + j] = f2b(W[k * HF + col]);
        }
    } else if (blockIdx.x == 32) {
        bucketCur[threadIdx.x] = threadIdx.x * BCAP;
    } else {
        pooled[(blockIdx.x - 33) * 256 + threadIdx.x] = 0.f;
    }
}

// ======================= bucketed CSR build (1024-thread wide versions) ==========
__device__ __forceinline__ void dev_bpart(int bx, const int* __restrict__ esrc,
                                          const int* __restrict__ edst,
                                          int* __restrict__ bucketCur,
                                          u32* __restrict__ epart, int ne, int ntot) {
    __shared__ int cnt[256];
    __shared__ int base[256];
    int tid = threadIdx.x;                 // 0..1023
    int t0 = bx * CH, t1 = min(t0 + CH, ntot);
    if (tid < 256) cnt[tid] = 0;
    __syncthreads();
    int sreg[2], dreg[2];
    #pragma unroll
    for (int it = 0; it < 2; ++it) {
        int t = t0 + tid + it * 1024;
        int s = 0, d = -1;
        if (t < t1) {
            if (t < ne) { s = esrc[t]; d = edst[t]; }
            else        { s = t - ne; d = s; }
            atomicAdd(&cnt[d >> 8], 1);
        }
        sreg[it] = s; dreg[it] = d;
    }
    __syncthreads();
    if (tid < 256) {
        int c = cnt[tid];
        base[tid] = c ? atomicAdd(&bucketCur[tid], c) : 0;
        cnt[tid] = 0;
    }
    __syncthreads();
    #pragma unroll
    for (int it = 0; it < 2; ++it) {
        int d = dreg[it];
        if (d >= 0) {
            int b = d >> 8;
            int pos = base[b] + atomicAdd(&cnt[b], 1);
            epart[pos] = ((u32)sreg[it] << 8) | (u32)(d & 255);
        }
    }
}

__device__ __forceinline__ void dev_bcsr(int bx, const u32* __restrict__ epart,
                                         const int* __restrict__ bucketCur,
                                         int* __restrict__ rowbeg,
                                         int* __restrict__ rowend,
                                         int* __restrict__ colidx, int n) {
    __shared__ int deg[256], offs[256], curs[256], s[256];
    int b = bx, tid = threadIdx.x;         // 0..1023
    int e0 = b * BCAP, e1 = bucketCur[b];
    if (tid < 256) { deg[tid] = 0; curs[tid] = 0; }
    __syncthreads();
    for (int t = e0 + tid; t < e1; t += 1024)
        atomicAdd(&deg[epart[t] & 255u], 1);
    __syncthreads();
    int v = 0;
    if (tid < 256) { v = deg[tid]; s[tid] = v; }
    __syncthreads();
    int acc = v;
    for (int off = 1; off < 256; off <<= 1) {
        int t = (tid < 256 && tid >= off) ? s[tid - off] : 0;
        __syncthreads();
        if (tid < 256) { acc += t; s[tid] = acc; }
        __syncthreads();
    }
    if (tid < 256) {
        int excl = acc - v;
        offs[tid] = excl;
        int node = (b << 8) + tid;
        if (node < n) {
            rowbeg[node] = e0 + excl;
            rowend[node] = e0 + excl + v;
        }
    }
    __syncthreads();
    for (int t = e0 + tid; t < e1; t += 1024) {
        u32 e = epart[t];
        int l = e & 255u;
        int pos = e0 + offs[l] + atomicAdd(&curs[l], 1);
        colidx[pos] = (int)(e >> 8);
    }
}

// ======================= MFMA GEMM (LDS-staged B, +bias, + fused alpha dots) ==========
template<bool A32, bool Q8>
__device__ __forceinline__ void dev_gemm(int rowbase, const u16* __restrict__ Ab,
                                         const float* __restrict__ Af,
                                         const u16* __restrict__ Bp,
                                         const float* __restrict__ bias,
                                         const float* __restrict__ a_s,
                                         const float* __restrict__ a_d,
                                         float* __restrict__ as_,
                                         float* __restrict__ ad_,
                                         u16* __restrict__ C,
                                         u8* __restrict__ C8, int M) {
    __shared__ u16 Bs[HF * HF];            // 32 KB packed B panel
    {
        const uint4* Bg = (const uint4*)Bp;
        uint4* Bl = (uint4*)Bs;
        for (int i = threadIdx.x; i < HF * HF / 8; i += blockDim.x)
            Bl[i] = Bg[i];
    }
    __syncthreads();

    int lane = threadIdx.x & 63;
    int wave = threadIdx.x >> 6;
    int quad = lane >> 4, l16 = lane & 15;
    int m0 = rowbase + wave * 16;
    int arow = m0 + l16;
    bool aval = arow < M;
    const bf16x8* Av = A32 ? nullptr : (const bf16x8*)(Ab + (size_t)arow * HF);
    const bf16x8* Bv = (const bf16x8*)Bs;
    f32x4 acc[8] = {};

    #pragma unroll
    for (int kc = 0; kc < 4; ++kc) {
        bf16x8 a = {};
        if (aval) {
            if constexpr (A32) {
                const float* ap = Af + (size_t)arow * HF + kc * 32 + quad * 8;
                float4 f0 = *(const float4*)ap;
                float4 f1 = *(const float4*)(ap + 4);
                a[0] = (short)f2b(f0.x); a[1] = (short)f2b(f0.y);
                a[2] = (short)f2b(f0.z); a[3] = (short)f2b(f0.w);
                a[4] = (short)f2b(f1.x); a[5] = (short)f2b(f1.y);
                a[6] = (short)f2b(f1.z); a[7] = (short)f2b(f1.w);
            } else {
                a = Av[kc * 4 + quad];
            }
        }
        #pragma unroll
        for (int t = 0; t < 8; ++t)
            acc[t] = __builtin_amdgcn_mfma_f32_16x16x32_bf16(a, Bv[t * 256 + kc * 64 + lane],
                                                             acc[t], 0, 0, 0);
    }

    int orow0 = m0 + quad * 4;
    #pragma unroll
    for (int t = 0; t < 8; ++t) {
        float b4 = bias ? bias[t * 16 + l16] : 0.f;
        #pragma unroll
        for (int r = 0; r < 4; ++r) {
            int orow = orow0 + r;
            if (orow < M) {
                float v = acc[t][r] + b4;
                if constexpr (Q8) C8[(size_t)orow * HF + t * 16 + l16] = f2q(v);
                else              C [(size_t)orow * HF + t * 16 + l16] = f2b(v);
            }
        }
    }

    if (as_) {
        float avs[8], avd[8];
        #pragma unroll
        for (int t = 0; t < 8; ++t) {
            avs[t] = a_s[t * 16 + l16];
            avd[t] = a_d[t * 16 + l16];
        }
        #pragma unroll
        for (int r = 0; r < 4; ++r) {
            float ps = 0.f, pd = 0.f;
            #pragma unroll
            for (int t = 0; t < 8; ++t) {
                ps = fmaf(acc[t][r], avs[t], ps);
                pd = fmaf(acc[t][r], avd[t], pd);
            }
            #pragma unroll
            for (int o = 1; o < 16; o <<= 1) {
                ps += __shfl_xor(ps, o);
                pd += __shfl_xor(pd, o);
            }
            int row = orow0 + r;
            if (l16 == 0 && row < M) { as_[row] = ps; ad_[row] = pd; }
        }
    }
}

// ---- merged dispatch 1 (1024 threads): wide gemm0  ||  bucket partition ----
__global__ __launch_bounds__(1024) void k_gemm0_bpart(const float* __restrict__ x,
                                                      const u16* __restrict__ Wp,
                                                      const float* __restrict__ b0,
                                                      u16* __restrict__ hb, int M, int gemmbW,
                                                      const int* __restrict__ esrc,
                                                      const int* __restrict__ edst,
                                                      int* __restrict__ bucketCur,
                                                      u32* __restrict__ epart, int ne, int ntot) {
    if ((int)blockIdx.x < gemmbW)
        dev_gemm<true, false>(blockIdx.x * 256, nullptr, x, Wp, b0,
                              nullptr, nullptr, nullptr, nullptr, hb, nullptr, M);
    else
        dev_bpart(blockIdx.x - gemmbW, esrc, edst, bucketCur, epart, ne, ntot);
}

// ---- merged dispatch 2 (1024 threads): wide layer-0 gemm  ||  bucket CSR ----
__global__ __launch_bounds__(1024) void k_gemm1_bcsr(const u16* __restrict__ hb,
                                                     const u16* __restrict__ Bp,
                                                     const float* __restrict__ a_s,
                                                     const float* __restrict__ a_d,
                                                     float* __restrict__ as_,
                                                     float* __restrict__ ad_,
                                                     u8* __restrict__ hp8, int M, int gemmbW,
                                                     const u32* __restrict__ epart,
                                                     const int* __restrict__ bucketCur,
                                                     int* __restrict__ rowbeg,
                                                     int* __restrict__ rowend,
                                                     int* __restrict__ colidx, int n) {
    if ((int)blockIdx.x < gemmbW)
        dev_gemm<false, true>(blockIdx.x * 256, hb, nullptr, Bp, nullptr,
                              a_s, a_d, as_, ad_, nullptr, hp8, M);
    else
        dev_bcsr(blockIdx.x - gemmbW, epart, bucketCur, rowbeg, rowend, colidx, n);
}

// ---- standalone layer gemm (layers 2..L): 256-thread shape ----
__global__ __launch_bounds__(256) void k_gemm_layer(const u16* __restrict__ hb,
                                                    const u16* __restrict__ Bp,
                                                    const float* __restrict__ a_s,
                                                    const float* __restrict__ a_d,
                                                    float* __restrict__ as_,
                                                    float* __restrict__ ad_,
                                                    u8* __restrict__ hp8, int M) {
    dev_gemm<false, true>(blockIdx.x * 64, hb, nullptr, Bp, nullptr,
                          a_s, a_d, as_, ad_, nullptr, hp8, M);
}

// ======================= per-dst softmax aggregation (v4: 2 nodes/wave) ==========
__device__ __forceinline__ void agg_fma4(u32 v, float w,
                                         float& a0, float& a1, float& a2, float& a3) {
    f32x2 lo = __builtin_amdgcn_cvt_pk_f32_fp8((int)v, false);
    f32x2 hi = __builtin_amdgcn_cvt_pk_f32_fp8((int)v, true);
    a0 = fmaf(w, lo.x, a0); a1 = fmaf(w, lo.y, a1);
    a2 = fmaf(w, hi.x, a2); a3 = fmaf(w, hi.y, a3);
}

template<bool POOL>
__device__ __forceinline__ void dev_agg_item(int it, const int* __restrict__ rowbeg,
                                             const int* __restrict__ rowend,
                                             const int* __restrict__ colidx,
                                             const u8* __restrict__ hp8,
                                             const float* __restrict__ as_,
                                             const float* __restrict__ ad_,
                                             const float* __restrict__ bl,
                                             u16* __restrict__ hout,
                                             int n, int relu,
                                             const int* __restrict__ batch,
                                             float* __restrict__ pooled) {
    int wv = threadIdx.x >> 6;
    int lane = threadIdx.x & 63;
    int half = lane >> 5;
    int hl = lane & 31;
    int slot = wv * 2 + half;           // node slot in block (0..7)
    int node = it * 8 + slot;
    bool valid = node < n;
    int beg = 0, end = 0;
    float adi = 0.f;
    if (valid) { beg = rowbeg[node]; end = rowend[node]; adi = ad_[node]; }
    int deg = end - beg;
    int cnt = deg < 32 ? deg : 32;
    int ecmax = cnt > 1 ? cnt - 1 : 0;

    // lane hl owns edge hl of its node (first 32)
    int srcl = (hl < deg) ? colidx[beg + hl] : 0;

    // ---- prefetch rows for edges 0..15 (needs only srcl; hides under pass 1) ----
    u32 q[16];
    int pf = cnt < 16 ? cnt : 16;
    #pragma unroll
    for (int i = 0; i < 16; ++i) {
        int ec = i < cnt ? i : ecmax;
        int s = __shfl(srcl, ec, 32);
        if (i < pf) q[i] = ((const u32*)(hp8 + (size_t)s * HF))[hl];
    }

    // ---- pass 1: exp weights (no max-sub), 32-lane sum reduce ----
    float el = 0.f;
    if (hl < deg) {
        float e = as_[srcl] + adi;
        e = e > 0.f ? e : NEG * e;
        el = __expf(e);
    }
    float ssum = el;
    for (int jj = beg + 32 + hl; jj < end; jj += 32) {
        float e = as_[colidx[jj]] + adi;
        e = e > 0.f ? e : NEG * e;
        ssum += __expf(e);
    }
    #pragma unroll
    for (int off = 16; off; off >>= 1) ssum += __shfl_xor(ssum, off, 32);
    float wl = el;              // UNNORMALIZED edge weight (1/sum in epilogue)

    // ---- pass 2: consume prefetched edges ----
    float a0 = 0.f, a1 = 0.f, a2 = 0.f, a3 = 0.f;
    #pragma unroll
    for (int i = 0; i < 16; ++i) {
        float w = (i < cnt) ? __shfl(wl, i, 32) : 0.f;
        if (i < pf) agg_fma4(q[i], w, a0, a1, a2, a3);
    }
    // remainder edges 16..cnt-1: batched 8-at-a-time (loads independent)
    for (int base = 16; base < cnt; base += 8) {
        u32 r[8];
        int mrem = cnt - base < 8 ? cnt - base : 8;
        #pragma unroll
        for (int i = 0; i < 8; ++i) {
            int ec = base + i < cnt ? base + i : ecmax;
            int s = __shfl(srcl, ec, 32);
            if (i < mrem) r[i] = ((const u32*)(hp8 + (size_t)s * HF))[hl];
        }
        #pragma unroll
        for (int i = 0; i < 8; ++i) {
            if (i < mrem) {
                float w = __shfl(wl, base + i, 32);
                agg_fma4(r[i], w, a0, a1, a2, a3);
            }
        }
    }
    // rare deg>32 tail: all 32 lanes of the half, uniform weight per edge
    for (int jj = beg + 32; jj < end; ++jj) {
        int s = colidx[jj];
        float e = as_[s] + adi;
        e = e > 0.f ? e : NEG * e;
        float w = __expf(e);
        u32 v = ((const u32*)(hp8 + (size_t)s * HF))[hl];
        agg_fma4(v, w, a0, a1, a2, a3);
    }

    if constexpr (!POOL) {
        if (valid) {
            float inv = 1.f / ssum;
            float4 bb = ((const float4*)bl)[hl];
            a0 = fmaf(a0, inv, bb.x); a1 = fmaf(a1, inv, bb.y);
            a2 = fmaf(a2, inv, bb.z); a3 = fmaf(a3, inv, bb.w);
            if (relu) {
                a0 = fmaxf(a0, 0.f); a1 = fmaxf(a1, 0.f);
                a2 = fmaxf(a2, 0.f); a3 = fmaxf(a3, 0.f);
            }
            uint2 o;
            o.x = ((u32)f2b(a1) << 16) | (u32)f2b(a0);
            o.y = ((u32)f2b(a3) << 16) | (u32)f2b(a2);
            ((uint2*)(hout + (size_t)node * HF))[hl] = o;
        }
    } else {
        __shared__ float ptile[8][HF];
        {
            float inv = valid ? 1.f / ssum : 0.f;
            float4 bb = ((const float4*)bl)[hl];
            ptile[slot][hl * 4 + 0] = valid ? fmaf(a0, inv, bb.x) : 0.f;
            ptile[slot][hl * 4 + 1] = valid ? fmaf(a1, inv, bb.y) : 0.f;
            ptile[slot][hl * 4 + 2] = valid ? fmaf(a2, inv, bb.z) : 0.f;
            ptile[slot][hl * 4 + 3] = valid ? fmaf(a3, inv, bb.w) : 0.f;
        }
        __syncthreads();
        int tid = threadIdx.x;
        if (tid < HF) {
            float a = 0.f;
            int curb = -1;
            #pragma unroll
            for (int s2 = 0; s2 < 8; ++s2) {
                int nd = it * 8 + s2;
                if (nd < n) {
                    int b = batch[nd];
                    if (b != curb) {
                        if (curb >= 0) atomicAdd(&pooled[curb * HF + tid], a);
                        curb = b;
                        a = 0.f;
                    }
                    a += ptile[s2][tid];
                }
            }
            if (curb >= 0) atomicAdd(&pooled[curb * HF + tid], a);
        }
    }
}

__global__ __launch_bounds__(256) void k_agg(const int* __restrict__ rowbeg,
                                             const int* __restrict__ rowend,
                                             const int* __restrict__ colidx,
                                             const u8* __restrict__ hp8,
                                             const float* __restrict__ as_,
                                             const float* __restrict__ ad_,
                                             const float* __restrict__ bl,
                                             u16* __restrict__ hout,
                                             int n, int relu) {
    dev_agg_item<false>(blockIdx.x, rowbeg, rowend, colidx, hp8, as_, ad_, bl,
                        hout, n, relu, nullptr, nullptr);
}

// final layer: agg (no relu) + fused global_add_pool
__global__ __launch_bounds__(256) void k_agg_pool(const int* __restrict__ rowbeg,
                                                  const int* __restrict__ rowend,
                                                  const int* __restrict__ colidx,
                                                  const u8* __restrict__ hp8,
                                                  const float* __restrict__ as_,
                                                  const float* __restrict__ ad_,
                                                  const float* __restrict__ bl,
                                                  int n,
                                                  const int* __restrict__ batch,
                                                  float* __restrict__ pooled) {
    dev_agg_item<true>(blockIdx.x, rowbeg, rowend, colidx, hp8, as_, ad_, bl,
                       nullptr, n, 0, batch, pooled);
}

__global__ void k_final(const float* __restrict__ pooled, const float* __restrict__ Wf,
                        const float* __restrict__ bf, float* __restrict__ out) {
    int g = blockIdx.x, o = threadIdx.x;   // 64 threads
    float acc = bf[o];
    #pragma unroll 8
    for (int k = 0; k < HF; ++k) acc = fmaf(pooled[g * HF + k], Wf[k * OUTF + o], acc);
    out[g * OUTF + o] = acc;
}

// ======================= launch =======================
extern "C" void kernel_launch(void* const* d_in, const int* in_sizes, int n_in,
                              void* d_out, int out_size, void* d_ws, size_t ws_size,
                              hipStream_t stream) {
    const float* x      = (const float*)d_in[0];
    const int*   edge   = (const int*)d_in[1];
    const int*   batch  = (const int*)d_in[2];
    const float* W0     = (const float*)d_in[3];
    const float* b0     = (const float*)d_in[4];
    const float* Wl     = (const float*)d_in[5];
    const float* a_src  = (const float*)d_in[6];
    const float* a_dst  = (const float*)d_in[7];
    const float* bl     = (const float*)d_in[8];
    const float* Wf     = (const float*)d_in[9];
    const float* bf     = (const float*)d_in[10];
    float* out = (float*)d_out;

    const int N  = in_sizes[2];
    const int E  = in_sizes[1] / 2;
    const int Et = E + N;
    const int L  = 3;
    const int NB = (N + 255) >> 8;               // buckets (<= 256)

    char* ws = (char*)d_ws;
    size_t off = 0;
    auto alloc = [&](size_t bytes) { char* p = ws + off; off += (bytes + 255) & ~(size_t)255; return p; };
    u16*   hb      = (u16*)alloc((size_t)N * HF * 2);
    u8*    hp8     = (u8*)alloc((size_t)N * HF);
    u16*   Wp      = (u16*)alloc((size_t)4 * HF * HF * 2);
    float* as_     = (float*)alloc((size_t)N * 4);
    float* ad_     = (float*)alloc((size_t)N * 4);
    int*   rowbeg  = (int*)alloc((size_t)N * 4);
    int*   rowend  = (int*)alloc((size_t)N * 4);
    int*   colidx  = (int*)alloc((size_t)NB * BCAP * 4);
    u32*   epart   = (u32*)alloc((size_t)NB * BCAP * 4);
    int*   bucketCur = (int*)alloc(256 * 4);
    float* pooled  = (float*)alloc((size_t)GCOUNT * HF * 4);
    (void)ws_size; (void)n_in; (void)out_size;

    const int wb8    = (N + 7) / 8;              // agg kernels: 8 nodes/block
    const int gemmb  = (N + 63) / 64;            // 256-thread gemms
    const int gemmbW = (N + 255) / 256;          // 1024-thread wide gemms
    const int partb  = (Et + CH - 1) / CH;

    const int* esrc = edge;
    const int* edst = edge + E;

    // --- pack weights + init bucketCur + zero pooled (one launch) ---
    k_pack_init<<<65, 256, 0, stream>>>(W0, Wl, Wp, bucketCur, pooled);

    // --- wide gemm0 (x @ W0 + b0)  ||  bucket partition (1024-thread blocks) ---
    k_gemm0_bpart<<<gemmbW + partb, 1024, 0, stream>>>(x, Wp, b0, hb, N, gemmbW,
                                                       esrc, edst, bucketCur, epart, E, Et);

    // --- wide layer-0 gemm (+dots, fp8 out)  ||  bucket CSR (1024-thread blocks) ---
    k_gemm1_bcsr<<<gemmbW + NB, 1024, 0, stream>>>(hb, Wp + (size_t)1 * HF * HF,
                                                   a_src, a_dst, as_, ad_, hp8, N, gemmbW,
                                                   epart, bucketCur, rowbeg, rowend, colidx, N);

    // --- GAT layers; final layer fuses global_add_pool ---
    for (int l = 0; l < L; ++l) {
        if (l > 0)
            k_gemm_layer<<<gemmb, 256, 0, stream>>>(hb, Wp + (size_t)(l + 1) * HF * HF,
                                                    a_src + l * HF, a_dst + l * HF,
                                                    as_, ad_, hp8, N);
        if (l < L - 1)
            k_agg<<<wb8, 256, 0, stream>>>(rowbeg, rowend, colidx, hp8, as_, ad_,
                                           bl + l * HF, hb, N, 1);
        else
            k_agg_pool<<<wb8, 256, 0, stream>>>(rowbeg, rowend, colidx, hp8, as_, ad_,
                                                bl + l * HF, N, batch, pooled);
    }

    // --- final linear ---
    k_final<<<GCOUNT, OUTF, 0, stream>>>(pooled, Wf, bf, out);
}